// Round 2
// baseline (349.467 us; speedup 1.0000x reference)
//
#include <hip/hip_runtime.h>
#include <math.h>

#define IMG_W 8192
#define PATCH 32
#define NPATCH 65536      // 256*256 patches
#define NBLK   16384      // kernel A blocks (4 patches/block, 1 per wave)

// ---------------------------------------------------------------------------
// Kernel A: fused patch-mean + loss terms.
// One wave (64 lanes) per 32x32 patch; 4 waves (4 patches) per block.
// Lane layout per iteration i (0..3): row i*8 + (lane>>3), float4 col (lane&7)
// -> each 8-lane group reads 128 contiguous 128B-aligned bytes (full lines).
// After the wave reduction, lane 0 computes the pos/neg term for its patch;
// thread 0 combines the block's 4 patches and writes SoA partials (no atomics,
// no memset needed -- every slot written unconditionally).
// ---------------------------------------------------------------------------
__global__ __launch_bounds__(256) void fused_patch_loss_kernel(
    const float* __restrict__ x, const float* __restrict__ tmask,
    float* __restrict__ p_pos, float* __restrict__ p_neg,
    float* __restrict__ p_cnt)
{
    const int wave  = threadIdx.x >> 6;          // 0..3
    const int lane  = threadIdx.x & 63;
    const int patch = blockIdx.x * 4 + wave;     // one patch per wave
    const int ph = patch >> 8;                   // 0..255
    const int pw = patch & 255;                  // 0..255

    const float* base = x + (size_t)(ph * PATCH) * IMG_W + (size_t)(pw * PATCH);
    const int r0 = lane >> 3;    // 0..7
    const int cv = lane & 7;     // float4 index within 128B row segment

    float s = 0.0f;
#pragma unroll
    for (int i = 0; i < 4; ++i) {
        const float4 v = *reinterpret_cast<const float4*>(
            base + (size_t)(i * 8 + r0) * IMG_W + cv * 4);
        s += (v.x + v.y) + (v.z + v.w);
    }

    // wave-64 reduction
#pragma unroll
    for (int off = 32; off >= 1; off >>= 1)
        s += __shfl_down(s, off, 64);

    __shared__ float s_pos[4], s_neg[4], s_cnt[4];
    if (lane == 0) {
        const float m = s * (1.0f / 1024.0f);
        const float t = tmask[patch];
        // logpdf = -0.5*z^2 - log(std*sqrt(2*pi));  log(0.04*sqrt(2pi)) = -2.2999373
        const float z = (m - 0.34f) * 25.0f;
        const float logpdf = -0.5f * z * z + 2.2999373f;
        const float pterm = -logf(expf(logpdf) + 1e-6f);
        const float nterm = m * m;
        const bool pos = (t >= 0.5f);
        s_pos[wave] = pos ? pterm : 0.0f;
        s_neg[wave] = pos ? 0.0f  : nterm;
        s_cnt[wave] = pos ? 1.0f  : 0.0f;
    }
    __syncthreads();

    if (threadIdx.x == 0) {
        p_pos[blockIdx.x] = (s_pos[0] + s_pos[1]) + (s_pos[2] + s_pos[3]);
        p_neg[blockIdx.x] = (s_neg[0] + s_neg[1]) + (s_neg[2] + s_neg[3]);
        p_cnt[blockIdx.x] = (s_cnt[0] + s_cnt[1]) + (s_cnt[2] + s_cnt[3]);
    }
}

// ---------------------------------------------------------------------------
// Kernel B: single-block reduction of 16384 partials x3 + finalize scalar.
// 1024 threads (16 waves); coalesced strided reads; shuffle + LDS reduce.
// ---------------------------------------------------------------------------
__global__ __launch_bounds__(1024) void finalize_reduce_kernel(
    const float* __restrict__ p_pos, const float* __restrict__ p_neg,
    const float* __restrict__ p_cnt, float* __restrict__ out)
{
    float pos = 0.0f, neg = 0.0f, cnt = 0.0f;
#pragma unroll
    for (int i = threadIdx.x; i < NBLK; i += 1024) {
        pos += p_pos[i];
        neg += p_neg[i];
        cnt += p_cnt[i];
    }

#pragma unroll
    for (int off = 32; off >= 1; off >>= 1) {
        pos += __shfl_down(pos, off, 64);
        neg += __shfl_down(neg, off, 64);
        cnt += __shfl_down(cnt, off, 64);
    }

    __shared__ float sp[16], sn[16], sc[16];
    const int wave = threadIdx.x >> 6;
    const int lane = threadIdx.x & 63;
    if (lane == 0) { sp[wave] = pos; sn[wave] = neg; sc[wave] = cnt; }
    __syncthreads();

    if (threadIdx.x == 0) {
        float P = 0.0f, N = 0.0f, C = 0.0f;
#pragma unroll
        for (int w = 0; w < 16; ++w) { P += sp[w]; N += sn[w]; C += sc[w]; }
        out[0] = P / C + N / ((float)NPATCH - C);
    }
}

extern "C" void kernel_launch(void* const* d_in, const int* in_sizes, int n_in,
                              void* d_out, int out_size, void* d_ws, size_t ws_size,
                              hipStream_t stream)
{
    const float* unet  = (const float*)d_in[0];   // [1,1,8192,8192] fp32
    const float* trans = (const float*)d_in[1];   // [1,256,256] fp32
    float* out = (float*)d_out;                   // scalar fp32

    float* p_pos = (float*)d_ws;                  // [16384]
    float* p_neg = p_pos + NBLK;                  // [16384]
    float* p_cnt = p_neg + NBLK;                  // [16384]

    fused_patch_loss_kernel<<<NBLK, 256, 0, stream>>>(unet, trans, p_pos, p_neg, p_cnt);
    finalize_reduce_kernel<<<1, 1024, 0, stream>>>(p_pos, p_neg, p_cnt, out);
}